// Round 10
// baseline (202.994 us; speedup 1.0000x reference)
//
#include <hip/hip_runtime.h>

// ---------------------------------------------------------------------------
// Causal single-head attention, B=64 T=512 C=768 H=72, fp32 in/out.
// cast_w: W -> wbt bf16 [3][80][768] (transposed, padded, Wq pre-scaled)
// proj:   R5/R8 counted-vmcnt pipeline (plain x loads).
// attn (R9): NO LDS STAGING, NO BARRIERS. K/V are L2-resident (~1.5 MB/XCD);
//         MFMA operands read directly from Kg/Vt (Common-mistake #7: don't
//         stage cache-fit data). Per-wave lp kept for the P layout transform.
//         R6/R7 split: A2 ~ 22 us vs ~10 floor; the per-iter vmcnt(0)+barrier
//         drain x9 was the suspect — this removes the sync structure wholesale.
// ---------------------------------------------------------------------------

typedef short bf16x8 __attribute__((ext_vector_type(8)));
typedef float f32x4 __attribute__((ext_vector_type(4)));
typedef float f32x4v __attribute__((ext_vector_type(4)));

#define DEVI __device__ __forceinline__
#define SB0() __builtin_amdgcn_sched_barrier(0)

DEVI unsigned f2bf(float f) {  // fp32 -> bf16 RNE (low 16 of result)
  unsigned u = __builtin_bit_cast(unsigned, f);
  return (u + 0x7fffu + ((u >> 16) & 1u)) >> 16;
}
DEVI unsigned pk2(float a, float b) { return f2bf(a) | (f2bf(b) << 16); }

DEVI void async16(void* lds, const void* g) {  // global->LDS, lane*16B
  __builtin_amdgcn_global_load_lds(
      (const __attribute__((address_space(1))) unsigned int*)g,
      (__attribute__((address_space(3))) unsigned int*)lds, 16, 0, 0);
}

// ---------------------------------------------------------------- cast_w ----
__global__ __launch_bounds__(256) void cast_w_k(const float* __restrict__ Wk,
                                                const float* __restrict__ Wq,
                                                const float* __restrict__ Wv,
                                                unsigned short* __restrict__ wbt) {
  __shared__ float ldsT[72][65];
  const int mat = blockIdx.x / 12, kc = blockIdx.x % 12;
  const float* W = (mat == 0) ? Wk : (mat == 1) ? Wq : Wv;
  const float sc = (mat == 1) ? 0.11785113019775793f : 1.0f;  // 72^-0.5 in q
  const float* src = W + kc * 64 * 72;
  for (int i = threadIdx.x; i < 1152; i += 256) {
    float4 d = *(const float4*)(src + i * 4);
    int e = i * 4;
    ldsT[e % 72][e / 72] = d.x;
    ldsT[(e + 1) % 72][(e + 1) / 72] = d.y;
    ldsT[(e + 2) % 72][(e + 2) / 72] = d.z;
    ldsT[(e + 3) % 72][(e + 3) / 72] = d.w;
  }
  __syncthreads();
  for (int c = threadIdx.x; c < 640; c += 256) {
    int h = c >> 3, kb = (c & 7) * 8;
    uint4 o = {0u, 0u, 0u, 0u};
    if (h < 72) {
      const float* rowp = &ldsT[h][kb];
      o.x = pk2(rowp[0] * sc, rowp[1] * sc);
      o.y = pk2(rowp[2] * sc, rowp[3] * sc);
      o.z = pk2(rowp[4] * sc, rowp[5] * sc);
      o.w = pk2(rowp[6] * sc, rowp[7] * sc);
    }
    *(uint4*)(wbt + ((size_t)mat * 80 + h) * 768 + kc * 64 + kb) = o;
  }
}

// ------------------------------------------------------------------ proj ----
// grid 512, 256 thr / 4 waves, 2 blocks/CU (76 KB LDS). M=64, N=240, BK=64.
// Counted-vmcnt schedule per iter t:
//   issue_w(t+1)->buf^1 ; issue_x(t+2)->regs ; compute(buf) ;
//   write_x(t+1)->buf^1 ; s_waitcnt vmcnt(4) lgkmcnt(0) ; s_barrier
struct ProjSmem {
  union {
    struct {
      short x[2][64 * 64];   // 2 x 8 KB
      short w[2][240 * 64];  // 2 x 30 KB
    } s;
    short t[80 * 72];  // V-transpose
  };
};

__global__ __launch_bounds__(256, 2) void proj_k(
    const float* __restrict__ x, const unsigned short* __restrict__ wbt,
    unsigned short* __restrict__ Kg, unsigned short* __restrict__ Qg,
    unsigned short* __restrict__ Vt) {
  __shared__ __align__(16) ProjSmem sm;
  const int row0 = blockIdx.x * 64;
  const int tid = threadIdx.x, wave = tid >> 6, lane = tid & 63;
  const int quad = lane >> 4, l16 = lane & 15;
  const int mg = wave >> 1, ng = wave & 1;
  const int ntile0 = ng * 8, ntn = ng ? 7 : 8;

  const int t0row = tid >> 3, tcb = tid & 7;  // x: 512 tasks = 64 rows x 8 cb
  const int wr8 = lane >> 3, wcb = lane & 7;  // W: 30 insts of 8 rows

  f32x4 acc[2][8] = {};  // [mt][j]; ng==1 uses j<7

  f32x4v xa0[2], xb0[2], xa1[2], xb1[2];  // two x prefetch sets (RA, RB)

  auto issue_x = [&](int k0, f32x4v* Ar, f32x4v* Br) {
    const float* g0 = x + (size_t)(row0 + t0row) * 768 + k0 + tcb * 8;
    Ar[0] = *(const f32x4v*)g0;
    Br[0] = *(const f32x4v*)(g0 + 4);
    const float* g1 = g0 + (size_t)32 * 768;
    Ar[1] = *(const f32x4v*)g1;
    Br[1] = *(const f32x4v*)(g1 + 4);
  };
  auto issue_w = [&](int k0, int nb) {
#pragma unroll
    for (int j = 0; j < 8; ++j) {
      int inst = j * 4 + wave;  // 0..31, use 0..29
      if (inst < 30) {
        int r = inst * 8 + wr8;
        async16(&sm.s.w[nb][inst * 512],
                wbt + (size_t)r * 768 + k0 + ((wcb ^ (r & 7)) * 8));
      }
    }
  };
  auto write_x = [&](int nb, const f32x4v* Ar, const f32x4v* Br) {
    uint4 o0 = {pk2(Ar[0].x, Ar[0].y), pk2(Ar[0].z, Ar[0].w),
                pk2(Br[0].x, Br[0].y), pk2(Br[0].z, Br[0].w)};
    *(uint4*)&sm.s.x[nb][t0row * 64 + ((tcb ^ (t0row & 7)) * 8)] = o0;
    int r1 = t0row + 32;
    uint4 o1 = {pk2(Ar[1].x, Ar[1].y), pk2(Ar[1].z, Ar[1].w),
                pk2(Br[1].x, Br[1].y), pk2(Br[1].z, Br[1].w)};
    *(uint4*)&sm.s.x[nb][r1 * 64 + ((tcb ^ (r1 & 7)) * 8)] = o1;
  };
  auto compute = [&](int cb) {
#pragma unroll
    for (int ks = 0; ks < 2; ++ks) {
      const int pblk = ((ks << 2) | quad) ^ (l16 & 7);  // 8-block XOR swizzle
      bf16x8 af[2];
#pragma unroll
      for (int mt = 0; mt < 2; ++mt)
        af[mt] = *(const bf16x8*)&sm.s.x[cb][(mg * 32 + mt * 16 + l16) * 64 + pblk * 8];
#pragma unroll
      for (int j = 0; j < 8; ++j)
        if (j < ntn) {
          int nt = ntile0 + j;
          bf16x8 bfr = *(const bf16x8*)&sm.s.w[cb][(nt * 16 + l16) * 64 + pblk * 8];
          acc[0][j] = __builtin_amdgcn_mfma_f32_16x16x32_bf16(af[0], bfr, acc[0][j], 0, 0, 0);
          acc[1][j] = __builtin_amdgcn_mfma_f32_16x16x32_bf16(af[1], bfr, acc[1][j], 0, 0, 0);
        }
    }
  };

  // prologue: W0+x0 -> buf0; x1 -> RB; leave x1 in flight across barrier
  issue_w(0, 0);
  SB0();
  issue_x(0, xa0, xb0);
  write_x(0, xa0, xb0);  // compiler waits x0 (drains W0 too)
  SB0();
  issue_x(64, xa1, xb1);
  SB0();
  asm volatile("s_waitcnt vmcnt(4) lgkmcnt(0)" ::: "memory");
  SB0();
  __builtin_amdgcn_s_barrier();

  // main loop, unrolled x2 for static reg-set parity. x(t+1) in RB on even t.
  for (int t = 0; t < 10; t += 2) {
    // even iter t: compute buf0, stage t+1 -> buf1
    issue_w((t + 1) * 64, 1);
    SB0();
    issue_x((t + 2) * 64, xa0, xb0);
    SB0();
    compute(0);
    write_x(1, xa1, xb1);
    asm volatile("s_waitcnt vmcnt(4) lgkmcnt(0)" ::: "memory");
    SB0();
    __builtin_amdgcn_s_barrier();
    // odd iter t+1: compute buf1, stage t+2 -> buf0
    issue_w((t + 2) * 64, 0);
    SB0();
    issue_x((t + 3) * 64, xa1, xb1);
    SB0();
    compute(1);
    write_x(0, xa0, xb0);
    asm volatile("s_waitcnt vmcnt(4) lgkmcnt(0)" ::: "memory");
    SB0();
    __builtin_amdgcn_s_barrier();
  }
  // t = 10: last stage (x11 already in RB), no further x issue
  issue_w(11 * 64, 1);
  SB0();
  compute(0);
  write_x(1, xa1, xb1);
  asm volatile("s_waitcnt vmcnt(0) lgkmcnt(0)" ::: "memory");
  SB0();
  __builtin_amdgcn_s_barrier();
  compute(1);  // tile 11
  __syncthreads();

  // epilogue: K tiles nt 0..4, Q tiles 5..9 (rows of 104, pad 72..103 zero),
  // V tiles 10..14 via LDS transpose.
#pragma unroll
  for (int mt = 0; mt < 2; ++mt)
#pragma unroll
    for (int r = 0; r < 4; ++r) {
      int lrow64 = mg * 32 + mt * 16 + quad * 4 + r;
      size_t grow = (size_t)row0 + lrow64;
#pragma unroll
      for (int j = 0; j < 8; ++j)
        if (j < ntn) {
          int nt = ntile0 + j;
          float v = acc[mt][j][r];
          if (nt < 5) {
            Kg[grow * 104 + nt * 16 + l16] = (unsigned short)f2bf(v);
          } else if (nt < 10) {
            Qg[grow * 104 + (nt - 5) * 16 + l16] = (unsigned short)f2bf(v);
          } else {
            sm.t[((nt - 10) * 16 + l16) * 72 + lrow64] = (short)f2bf(v);
          }
        }
      unsigned short* p = (ng ? Qg : Kg) + grow * 104;
      p[80 + l16] = 0;
      if (l16 < 8) p[96 + l16] = 0;
    }
  __syncthreads();
  int b = blockIdx.x >> 3, t0 = (blockIdx.x & 7) * 64;
  const uint4 ones = {0x3F803F80u, 0x3F803F80u, 0x3F803F80u, 0x3F803F80u};
  for (int c = tid; c < 640; c += 256) {
    int hr = c >> 3, tc = (c & 7) * 8;
    uint4 d = *(const uint4*)&sm.t[hr * 72 + tc];
    if (hr == 72) d = ones;
    *(uint4*)(Vt + ((size_t)b * 80 + hr) * 512 + t0 + tc) = d;
  }
}

// ------------------------------------------------------------------ attn ----
// R9: NO staging, NO barriers. 512 blocks (balance-permuted), 4 independent
// waves, 16 Q-rows/wave, TK=64. K/V read directly from L2-resident Kg/Vt.
// lp (per-wave, 9 KB total) kept for the P A-layout transform.
__global__ __launch_bounds__(256, 2) void attn_k(
    const unsigned short* __restrict__ Qg, const unsigned short* __restrict__ Kg,
    const unsigned short* __restrict__ Vt, float* __restrict__ out) {
  __shared__ __align__(16) short lp[4][16 * 72];  // per-wave P, stride 72

  int idx = (blockIdx.x < 256) ? blockIdx.x : 767 - blockIdx.x;
  const int qb = 7 - (idx >> 6), b = idx & 63;
  const int tid = threadIdx.x, wave = tid >> 6, lane = tid & 63;
  const int quad = lane >> 4, l16 = lane & 15;
  const int trow0 = qb * 64 + wave * 16;

  bf16x8 qf[3];
#pragma unroll
  for (int kt = 0; kt < 3; ++kt)
    qf[kt] = *(const bf16x8*)(Qg + ((size_t)b * 512 + trow0 + l16) * 104 + kt * 32 + quad * 8);

  // row bases for direct operand reads
  const unsigned short* Krow = Kg + ((size_t)b * 512 + l16) * 104;   // + (s0+nt*16)*104
  const unsigned short* Vrow = Vt + ((size_t)b * 80 + l16) * 512;    // + nt*16*512 + s0

  f32x4 o[5] = {};

  for (int kb = 0; kb <= qb; ++kb) {
    const int s0 = kb * 64;
    const bool diag = (kb == qb);
    const int nact = diag ? (wave + 1) : 4;

    f32x4 sacc[4] = {};
#pragma unroll
    for (int kt = 0; kt < 3; ++kt)
      for (int nt = 0; nt < nact; ++nt) {
        bf16x8 kf = *(const bf16x8*)(Krow + (size_t)(s0 + nt * 16) * 104 + kt * 32 + quad * 8);
        sacc[nt] = __builtin_amdgcn_mfma_f32_16x16x32_bf16(qf[kt], kf, sacc[nt], 0, 0, 0);
      }
    if (diag) {  // mask the straddling tile nt == wave
      int nt = wave;
#pragma unroll
      for (int r = 0; r < 4; ++r) {
        int t = trow0 + quad * 4 + r;
        if (s0 + nt * 16 + l16 > t) sacc[nt][r] = -1e30f;
      }
    }
    // p = exp(s) (no max subtraction), write to per-wave LDS in A-layout
#pragma unroll
    for (int nt = 0; nt < 4; ++nt)
#pragma unroll
      for (int r = 0; r < 4; ++r) {
        float p = (nt < nact) ? __expf(sacc[nt][r]) : 0.0f;
        lp[wave][(quad * 4 + r) * 72 + nt * 16 + l16] = (short)f2bf(p);
      }
    // O += P V^ (column 72 of V^ is ones -> denominator in o[4])
#pragma unroll
    for (int ks = 0; ks < 2; ++ks) {
      bf16x8 pf = *(const bf16x8*)&lp[wave][l16 * 72 + ks * 32 + quad * 8];
#pragma unroll
      for (int nt = 0; nt < 5; ++nt) {
        bf16x8 vf = *(const bf16x8*)(Vrow + (size_t)(nt * 16) * 512 + s0 + (((ks << 2) | quad)) * 8);
        o[nt] = __builtin_amdgcn_mfma_f32_16x16x32_bf16(pf, vf, o[nt], 0, 0, 0);
      }
    }
  }

#pragma unroll
  for (int r = 0; r < 4; ++r) {
    float l = __shfl(o[4][r], (lane & 48) | 8, 64);
    float inv = 1.0f / l;
    size_t t = (size_t)b * 512 + trow0 + quad * 4 + r;
#pragma unroll
    for (int nt = 0; nt < 5; ++nt) {
      int h = nt * 16 + l16;
      if (h < 72) out[t * 72 + h] = o[nt][r] * inv;
    }
  }
}

// ---------------------------------------------------------------------------
extern "C" void kernel_launch(void* const* d_in, const int* in_sizes, int n_in,
                              void* d_out, int out_size, void* d_ws, size_t ws_size,
                              hipStream_t stream) {
  const float* x  = (const float*)d_in[0];
  const float* Wk = (const float*)d_in[1];
  const float* Wq = (const float*)d_in[2];
  const float* Wv = (const float*)d_in[3];
  float* out = (float*)d_out;

  char* ws = (char*)d_ws;
  unsigned short* Kg  = (unsigned short*)(ws);             // 6,815,744
  unsigned short* Qg  = (unsigned short*)(ws + 6815744);   // 6,815,744
  unsigned short* Vt  = (unsigned short*)(ws + 13631488);  // 5,242,880
  unsigned short* wbt = (unsigned short*)(ws + 18874368);  //   368,640

  cast_w_k<<<36, 256, 0, stream>>>(Wk, Wq, Wv, wbt);
  proj_k<<<512, 256, 0, stream>>>(x, wbt, Kg, Qg, Vt);
  attn_k<<<512, 256, 0, stream>>>(Qg, Kg, Vt, out);
}

// Round 11
// 186.642 us; speedup vs baseline: 1.0876x; 1.0876x over previous
//
#include <hip/hip_runtime.h>

// ---------------------------------------------------------------------------
// Causal single-head attention, B=64 T=512 C=768 H=72, fp32 in/out.
// R10 = REVERT to best-measured configuration (R5, 187.66 us).
// Session budget (R6/R7 duplication measurements):
//   harness fixed ~131 us (poison fill 402MB + restore copy, 82-87% HBM peak)
//   cast ~3.5 | proj ~31 (floor ~19) | attn ~22 (floor ~10-13)
// Tried and nulled/regressed: proj dbuf (R4), counted-vmcnt (R5), plain-vs-nt
// x loads (R8), attn de-staging (R9, +14 us — staging earns its barriers).
// cast_w: W -> wbt bf16 [3][80][768] (transposed, padded, Wq pre-scaled)
// proj:   fused QKV GEMM, BK=64 dbuf, counted-vmcnt pipeline (x 2 tiles ahead
//         in regs, vmcnt(4) across s_barrier), x non-temporal.
// attn:   flash-style, no running max, TK=64, double-buffered K/V staging,
//         one barrier/iter, denominator via PV ones-column.
// ---------------------------------------------------------------------------

typedef short bf16x8 __attribute__((ext_vector_type(8)));
typedef float f32x4 __attribute__((ext_vector_type(4)));
typedef float f32x4v __attribute__((ext_vector_type(4)));

#define DEVI __device__ __forceinline__
#define SB0() __builtin_amdgcn_sched_barrier(0)

DEVI unsigned f2bf(float f) {  // fp32 -> bf16 RNE (low 16 of result)
  unsigned u = __builtin_bit_cast(unsigned, f);
  return (u + 0x7fffu + ((u >> 16) & 1u)) >> 16;
}
DEVI unsigned pk2(float a, float b) { return f2bf(a) | (f2bf(b) << 16); }

DEVI void async16(void* lds, const void* g) {  // global->LDS, lane*16B
  __builtin_amdgcn_global_load_lds(
      (const __attribute__((address_space(1))) unsigned int*)g,
      (__attribute__((address_space(3))) unsigned int*)lds, 16, 0, 0);
}

// ---------------------------------------------------------------- cast_w ----
__global__ __launch_bounds__(256) void cast_w_k(const float* __restrict__ Wk,
                                                const float* __restrict__ Wq,
                                                const float* __restrict__ Wv,
                                                unsigned short* __restrict__ wbt) {
  __shared__ float ldsT[72][65];
  const int mat = blockIdx.x / 12, kc = blockIdx.x % 12;
  const float* W = (mat == 0) ? Wk : (mat == 1) ? Wq : Wv;
  const float sc = (mat == 1) ? 0.11785113019775793f : 1.0f;  // 72^-0.5 in q
  const float* src = W + kc * 64 * 72;
  for (int i = threadIdx.x; i < 1152; i += 256) {
    float4 d = *(const float4*)(src + i * 4);
    int e = i * 4;
    ldsT[e % 72][e / 72] = d.x;
    ldsT[(e + 1) % 72][(e + 1) / 72] = d.y;
    ldsT[(e + 2) % 72][(e + 2) / 72] = d.z;
    ldsT[(e + 3) % 72][(e + 3) / 72] = d.w;
  }
  __syncthreads();
  for (int c = threadIdx.x; c < 640; c += 256) {
    int h = c >> 3, kb = (c & 7) * 8;
    uint4 o = {0u, 0u, 0u, 0u};
    if (h < 72) {
      const float* rowp = &ldsT[h][kb];
      o.x = pk2(rowp[0] * sc, rowp[1] * sc);
      o.y = pk2(rowp[2] * sc, rowp[3] * sc);
      o.z = pk2(rowp[4] * sc, rowp[5] * sc);
      o.w = pk2(rowp[6] * sc, rowp[7] * sc);
    }
    *(uint4*)(wbt + ((size_t)mat * 80 + h) * 768 + kc * 64 + kb) = o;
  }
}

// ------------------------------------------------------------------ proj ----
// grid 512, 256 thr / 4 waves, 2 blocks/CU (76 KB LDS). M=64, N=240, BK=64.
// Counted-vmcnt schedule per iter t:
//   issue_w(t+1)->buf^1 ; issue_x(t+2)->regs ; compute(buf) ;
//   write_x(t+1)->buf^1 ; s_waitcnt vmcnt(4) lgkmcnt(0) ; s_barrier
struct ProjSmem {
  union {
    struct {
      short x[2][64 * 64];   // 2 x 8 KB
      short w[2][240 * 64];  // 2 x 30 KB
    } s;
    short t[80 * 72];  // V-transpose
  };
};

__global__ __launch_bounds__(256, 2) void proj_k(
    const float* __restrict__ x, const unsigned short* __restrict__ wbt,
    unsigned short* __restrict__ Kg, unsigned short* __restrict__ Qg,
    unsigned short* __restrict__ Vt) {
  __shared__ __align__(16) ProjSmem sm;
  const int row0 = blockIdx.x * 64;
  const int tid = threadIdx.x, wave = tid >> 6, lane = tid & 63;
  const int quad = lane >> 4, l16 = lane & 15;
  const int mg = wave >> 1, ng = wave & 1;
  const int ntile0 = ng * 8, ntn = ng ? 7 : 8;

  const int t0row = tid >> 3, tcb = tid & 7;  // x: 512 tasks = 64 rows x 8 cb
  const int wr8 = lane >> 3, wcb = lane & 7;  // W: 30 insts of 8 rows

  f32x4 acc[2][8] = {};  // [mt][j]; ng==1 uses j<7

  f32x4v xa0[2], xb0[2], xa1[2], xb1[2];  // two x prefetch sets (RA, RB)

  auto issue_x = [&](int k0, f32x4v* Ar, f32x4v* Br) {
    const float* g0 = x + (size_t)(row0 + t0row) * 768 + k0 + tcb * 8;
    Ar[0] = __builtin_nontemporal_load((const f32x4v*)g0);
    Br[0] = __builtin_nontemporal_load((const f32x4v*)(g0 + 4));
    const float* g1 = g0 + (size_t)32 * 768;
    Ar[1] = __builtin_nontemporal_load((const f32x4v*)g1);
    Br[1] = __builtin_nontemporal_load((const f32x4v*)(g1 + 4));
  };
  auto issue_w = [&](int k0, int nb) {
#pragma unroll
    for (int j = 0; j < 8; ++j) {
      int inst = j * 4 + wave;  // 0..31, use 0..29
      if (inst < 30) {
        int r = inst * 8 + wr8;
        async16(&sm.s.w[nb][inst * 512],
                wbt + (size_t)r * 768 + k0 + ((wcb ^ (r & 7)) * 8));
      }
    }
  };
  auto write_x = [&](int nb, const f32x4v* Ar, const f32x4v* Br) {
    uint4 o0 = {pk2(Ar[0].x, Ar[0].y), pk2(Ar[0].z, Ar[0].w),
                pk2(Br[0].x, Br[0].y), pk2(Br[0].z, Br[0].w)};
    *(uint4*)&sm.s.x[nb][t0row * 64 + ((tcb ^ (t0row & 7)) * 8)] = o0;
    int r1 = t0row + 32;
    uint4 o1 = {pk2(Ar[1].x, Ar[1].y), pk2(Ar[1].z, Ar[1].w),
                pk2(Br[1].x, Br[1].y), pk2(Br[1].z, Br[1].w)};
    *(uint4*)&sm.s.x[nb][r1 * 64 + ((tcb ^ (r1 & 7)) * 8)] = o1;
  };
  auto compute = [&](int cb) {
#pragma unroll
    for (int ks = 0; ks < 2; ++ks) {
      const int pblk = ((ks << 2) | quad) ^ (l16 & 7);  // 8-block XOR swizzle
      bf16x8 af[2];
#pragma unroll
      for (int mt = 0; mt < 2; ++mt)
        af[mt] = *(const bf16x8*)&sm.s.x[cb][(mg * 32 + mt * 16 + l16) * 64 + pblk * 8];
#pragma unroll
      for (int j = 0; j < 8; ++j)
        if (j < ntn) {
          int nt = ntile0 + j;
          bf16x8 bfr = *(const bf16x8*)&sm.s.w[cb][(nt * 16 + l16) * 64 + pblk * 8];
          acc[0][j] = __builtin_amdgcn_mfma_f32_16x16x32_bf16(af[0], bfr, acc[0][j], 0, 0, 0);
          acc[1][j] = __builtin_amdgcn_mfma_f32_16x16x32_bf16(af[1], bfr, acc[1][j], 0, 0, 0);
        }
    }
  };

  // prologue: W0+x0 -> buf0; x1 -> RB; leave x1 in flight across barrier
  issue_w(0, 0);
  SB0();
  issue_x(0, xa0, xb0);
  write_x(0, xa0, xb0);  // compiler waits x0 (drains W0 too)
  SB0();
  issue_x(64, xa1, xb1);
  SB0();
  asm volatile("s_waitcnt vmcnt(4) lgkmcnt(0)" ::: "memory");
  SB0();
  __builtin_amdgcn_s_barrier();

  // main loop, unrolled x2 for static reg-set parity. x(t+1) in RB on even t.
  for (int t = 0; t < 10; t += 2) {
    // even iter t: compute buf0, stage t+1 -> buf1
    issue_w((t + 1) * 64, 1);
    SB0();
    issue_x((t + 2) * 64, xa0, xb0);
    SB0();
    compute(0);
    write_x(1, xa1, xb1);
    asm volatile("s_waitcnt vmcnt(4) lgkmcnt(0)" ::: "memory");
    SB0();
    __builtin_amdgcn_s_barrier();
    // odd iter t+1: compute buf1, stage t+2 -> buf0
    issue_w((t + 2) * 64, 0);
    SB0();
    issue_x((t + 3) * 64, xa1, xb1);
    SB0();
    compute(1);
    write_x(0, xa0, xb0);
    asm volatile("s_waitcnt vmcnt(4) lgkmcnt(0)" ::: "memory");
    SB0();
    __builtin_amdgcn_s_barrier();
  }
  // t = 10: last stage (x11 already in RB), no further x issue
  issue_w(11 * 64, 1);
  SB0();
  compute(0);
  write_x(1, xa1, xb1);
  asm volatile("s_waitcnt vmcnt(0) lgkmcnt(0)" ::: "memory");
  SB0();
  __builtin_amdgcn_s_barrier();
  compute(1);  // tile 11
  __syncthreads();

  // epilogue: K tiles nt 0..4, Q tiles 5..9 (rows of 104, pad 72..103 zero),
  // V tiles 10..14 via LDS transpose.
#pragma unroll
  for (int mt = 0; mt < 2; ++mt)
#pragma unroll
    for (int r = 0; r < 4; ++r) {
      int lrow64 = mg * 32 + mt * 16 + quad * 4 + r;
      size_t grow = (size_t)row0 + lrow64;
#pragma unroll
      for (int j = 0; j < 8; ++j)
        if (j < ntn) {
          int nt = ntile0 + j;
          float v = acc[mt][j][r];
          if (nt < 5) {
            Kg[grow * 104 + nt * 16 + l16] = (unsigned short)f2bf(v);
          } else if (nt < 10) {
            Qg[grow * 104 + (nt - 5) * 16 + l16] = (unsigned short)f2bf(v);
          } else {
            sm.t[((nt - 10) * 16 + l16) * 72 + lrow64] = (short)f2bf(v);
          }
        }
      unsigned short* p = (ng ? Qg : Kg) + grow * 104;
      p[80 + l16] = 0;
      if (l16 < 8) p[96 + l16] = 0;
    }
  __syncthreads();
  int b = blockIdx.x >> 3, t0 = (blockIdx.x & 7) * 64;
  const uint4 ones = {0x3F803F80u, 0x3F803F80u, 0x3F803F80u, 0x3F803F80u};
  for (int c = tid; c < 640; c += 256) {
    int hr = c >> 3, tc = (c & 7) * 8;
    uint4 d = *(const uint4*)&sm.t[hr * 72 + tc];
    if (hr == 72) d = ones;
    *(uint4*)(Vt + ((size_t)b * 80 + hr) * 512 + t0 + tc) = d;
  }
}

// ------------------------------------------------------------------ attn ----
// R5: 512 blocks (balance-permuted), 4 waves, 16 Q-rows/wave, TK=64,
// DOUBLE-BUFFERED K/V staging; stage(kb+1) issued before compute(kb);
// single barrier per iteration. 55 KB LDS -> 2 blocks/CU.
__global__ __launch_bounds__(256, 2) void attn_k(
    const unsigned short* __restrict__ Qg, const unsigned short* __restrict__ Kg,
    const unsigned short* __restrict__ Vt, float* __restrict__ out) {
  __shared__ __align__(16) short lk[2][64 * 104];  // 2 x 13 KB
  __shared__ __align__(16) short lv[2][80 * 64];   // 2 x 10 KB, XOR swizzle
  __shared__ __align__(16) short lp[4][16 * 72];   // per-wave P, stride 72

  int idx = (blockIdx.x < 256) ? blockIdx.x : 767 - blockIdx.x;
  const int qb = 7 - (idx >> 6), b = idx & 63;
  const int tid = threadIdx.x, wave = tid >> 6, lane = tid & 63;
  const int quad = lane >> 4, l16 = lane & 15;
  const int lrow = lane >> 3, lcb = lane & 7;
  const int trow0 = qb * 64 + wave * 16;

  bf16x8 qf[3];
#pragma unroll
  for (int kt = 0; kt < 3; ++kt)
    qf[kt] = *(const bf16x8*)(Qg + ((size_t)b * 512 + trow0 + l16) * 104 + kt * 32 + quad * 8);

  auto stage = [&](int kb, int pb) {
    const int s0 = kb * 64;
#pragma unroll
    for (int j = 0; j < 4; ++j) {  // K tile: 64 x 104 = 13 KiB linear
      int inst = j * 4 + wave;
      if (inst < 13)
        async16(&lk[pb][inst * 512], Kg + ((size_t)b * 512 + s0) * 104 + inst * 512 + lane * 8);
    }
    for (int j = wave; j < 10; j += 4) {  // V^T tile, swizzled source
      int r = j * 8 + lrow;
      async16(&lv[pb][j * 512], Vt + ((size_t)b * 80 + r) * 512 + s0 + (lcb ^ lrow) * 8);
    }
  };

  f32x4 o[5] = {};

  stage(0, 0);
  asm volatile("s_waitcnt vmcnt(0)" ::: "memory");
  SB0();
  __builtin_amdgcn_s_barrier();

  for (int kb = 0; kb <= qb; ++kb) {
    const int pb = kb & 1;
    const int s0 = kb * 64;
    const bool diag = (kb == qb);
    const int nact = diag ? (wave + 1) : 4;

    if (!diag) stage(kb + 1, pb ^ 1);  // prefetch next tile into other buffer
    SB0();

    f32x4 sacc[4] = {};
#pragma unroll
    for (int kt = 0; kt < 3; ++kt)
      for (int nt = 0; nt < nact; ++nt) {
        bf16x8 kf = *(const bf16x8*)&lk[pb][(nt * 16 + l16) * 104 + kt * 32 + quad * 8];
        sacc[nt] = __builtin_amdgcn_mfma_f32_16x16x32_bf16(qf[kt], kf, sacc[nt], 0, 0, 0);
      }
    if (diag) {  // mask the straddling tile nt == wave
      int nt = wave;
#pragma unroll
      for (int r = 0; r < 4; ++r) {
        int t = trow0 + quad * 4 + r;
        if (s0 + nt * 16 + l16 > t) sacc[nt][r] = -1e30f;
      }
    }
    // p = exp(s) (no max subtraction), write to per-wave LDS in A-layout
#pragma unroll
    for (int nt = 0; nt < 4; ++nt)
#pragma unroll
      for (int r = 0; r < 4; ++r) {
        float p = (nt < nact) ? __expf(sacc[nt][r]) : 0.0f;
        lp[wave][(quad * 4 + r) * 72 + nt * 16 + l16] = (short)f2bf(p);
      }
    // O += P V^ (column 72 of V^ is ones -> denominator in o[4])
#pragma unroll
    for (int ks = 0; ks < 2; ++ks) {
      bf16x8 pf = *(const bf16x8*)&lp[wave][l16 * 72 + ks * 32 + quad * 8];
      const int pblk = ((ks << 2) | quad) ^ (l16 & 7);
#pragma unroll
      for (int nt = 0; nt < 5; ++nt) {
        bf16x8 vf = *(const bf16x8*)&lv[pb][(nt * 16 + l16) * 64 + pblk * 8];
        o[nt] = __builtin_amdgcn_mfma_f32_16x16x32_bf16(pf, vf, o[nt], 0, 0, 0);
      }
    }
    if (!diag) {  // next-tile DMA done + this-tile LDS reads retired
      asm volatile("s_waitcnt vmcnt(0) lgkmcnt(0)" ::: "memory");
      SB0();
      __builtin_amdgcn_s_barrier();
    }
  }

#pragma unroll
  for (int r = 0; r < 4; ++r) {
    float l = __shfl(o[4][r], (lane & 48) | 8, 64);
    float inv = 1.0f / l;
    size_t t = (size_t)b * 512 + trow0 + quad * 4 + r;
#pragma unroll
    for (int nt = 0; nt < 5; ++nt) {
      int h = nt * 16 + l16;
      if (h < 72) out[t * 72 + h] = o[nt][r] * inv;
    }
  }
}

// ---------------------------------------------------------------------------
extern "C" void kernel_launch(void* const* d_in, const int* in_sizes, int n_in,
                              void* d_out, int out_size, void* d_ws, size_t ws_size,
                              hipStream_t stream) {
  const float* x  = (const float*)d_in[0];
  const float* Wk = (const float*)d_in[1];
  const float* Wq = (const float*)d_in[2];
  const float* Wv = (const float*)d_in[3];
  float* out = (float*)d_out;

  char* ws = (char*)d_ws;
  unsigned short* Kg  = (unsigned short*)(ws);             // 6,815,744
  unsigned short* Qg  = (unsigned short*)(ws + 6815744);   // 6,815,744
  unsigned short* Vt  = (unsigned short*)(ws + 13631488);  // 5,242,880
  unsigned short* wbt = (unsigned short*)(ws + 18874368);  //   368,640

  cast_w_k<<<36, 256, 0, stream>>>(Wk, Wq, Wv, wbt);
  proj_k<<<512, 256, 0, stream>>>(x, wbt, Kg, Qg, Vt);
  attn_k<<<512, 256, 0, stream>>>(Qg, Kg, Vt, out);
}